// Round 16
// baseline (368.315 us; speedup 1.0000x reference)
//
#include <hip/hip_runtime.h>
#include <math.h>

// TrajDecoder on MI355X (gfx950).  Round 16: R15 + ks-pair B prefetch + setprio.
//   R15 (best, 355us fused): 32x32x16, staged-once A in 64KB LDS reused for
//   h1/h2, B frag-packed from global/L2, 2 blocks/CU.  Remaining limiter:
//   lockstep B-load latency (L2 thrashed by hidden stream).  R16: each chunk's
//   B loads split into ks-pairs with 1-pair lookahead (live ~115 regs, no
//   spill) + s_setprio(1) around each 8-MFMA cluster (T5: helps when waves
//   drift phase in barrier-free loops).

#define KROWS 65536
#define DH 512

typedef _Float16 f16;
typedef _Float16 half8 __attribute__((ext_vector_type(8)));
typedef float floatx4 __attribute__((ext_vector_type(4)));
typedef float floatx16 __attribute__((ext_vector_type(16)));

#define WS_WF16   0
#define WS_W3F16  4194304
#define WS_PRED2D 4227072
#define WS_PART   5275648

// ---------------------------------------------------------------------------
// Weight conversion, 32x32 frag-packed layout (unchanged from R15):
//   region (m,l): 512KB at ml*262144 f16.  frag-block fb = nt32*32 + ks (1KB),
//   lane slot holds w[nt32*32 + (lane&31)][ks*16 + (lane>>5)*8 .. +8].
// ---------------------------------------------------------------------------
__global__ __launch_bounds__(256) void convert_weights(
    const float* __restrict__ w1, const float* __restrict__ w2,
    const float* __restrict__ w3, f16* __restrict__ wf16, f16* __restrict__ w3f16)
{
  int t = blockIdx.x * 256 + threadIdx.x;
  if (t < 262144) {
    int ml = t >> 15;              // (m,l) 0..7
    int mm = ml >> 1, l = ml & 1;
    int r = t & 32767;
    int fb = r >> 6;               // nt32*32 + ks, 0..511
    int lane = r & 63;
    int nt = fb >> 5, ks = fb & 31;
    int n = nt * 32 + (lane & 31);
    int k = ks * 16 + (lane >> 5) * 8;
    const float* src = (l ? w2 : w1) + (size_t)mm * 262144 + n * 512 + k;
    floatx4 u0 = *(const floatx4*)(src);
    floatx4 u1 = *(const floatx4*)(src + 4);
    half8 h;
    h[0] = (f16)u0[0]; h[1] = (f16)u0[1]; h[2] = (f16)u0[2]; h[3] = (f16)u0[3];
    h[4] = (f16)u1[0]; h[5] = (f16)u1[1]; h[6] = (f16)u1[2]; h[7] = (f16)u1[3];
    *(half8*)(wf16 + (size_t)ml * 262144 + fb * 512 + lane * 8) = h;
  } else {
    int j = t - 262144;
    if (j < 23 * DH) w3f16[j] = (f16)w3[j];
  }
}

// ---------------------------------------------------------------------------
// Fused 2-layer MLP + head.  grid = 4096 x 512 (8 waves).  Wave tile 64x64
// as 2x2 fragments of 32x32.  One head per block (head -> XCD pinning).
// LDS (STATIC 64KB): one region, 8 chunks of [64r x 64c] f16 swizzled;
//   lifecycle A -> h1 -> h2.  Swizzle: byte row*128 + (2c ^ ((row&7)<<4)).
// ---------------------------------------------------------------------------
__global__ __launch_bounds__(512, 4)
__attribute__((amdgpu_waves_per_eu(4, 4)))
void fused_kernel(
    const float* __restrict__ hidden,
    const f16* __restrict__ wf16,
    const f16* __restrict__ w3f16,
    const float* __restrict__ b1g,
    const float* __restrict__ b2g,
    const float* __restrict__ b3g,
    float* __restrict__ dout,
    float* __restrict__ pred2d)
{
  __shared__ __align__(16) unsigned char smem[65536];

  const int bid = blockIdx.x;
  const int rr  = bid & 7;
  const int m   = rr >> 1;                            // head -> XCD pair
  const int row_tile = ((bid >> 3) << 1) | (rr & 1);  // 0..1023
  const int r0  = row_tile * 64;
  const int tid = threadIdx.x;
  const int w   = __builtin_amdgcn_readfirstlane(tid >> 6);  // SGPR wave idx
  const int lane = tid & 63;
  const int l15 = lane & 15;
  const int lg  = lane >> 4;
  const int l31 = lane & 31;
  const int hi  = lane >> 5;

  // --- 32x32 A-frag read offsets (rows mt*32+l31, k = ks*16 + hi*8) ---
  const int arow32 = l31 * 128;
  const int hi16   = hi * 16;
  const int sw31   = (lane & 7) << 4;   // (row&7)<<4, row = mt*32+l31
  auto aread32 = [&](int g, int mt, int ks) -> half8 {
    return *(const half8*)(smem + g * 8192 + mt * 4096 + arow32
                           + ((ks * 32 + hi16) ^ sw31));
  };
  // --- 16x16 A-frag read (head GEMM path; rows 16-based) ---
  const int arow16 = l15 * 128;
  const int ao16   = (lg * 16) ^ ((l15 & 7) << 4);
  auto aread16 = [&](int q, int mt) -> half8 {
    return *(const half8*)(smem + (q >> 1) * 8192 + mt * 2048 + arow16
                           + (ao16 ^ ((q & 1) << 6)));
  };
  // --- B-frag (layer l, chunk g in [0,8), k-step ks in [0,4), nt in [0,2)) ---
  const f16* bptr = wf16 + (size_t)(m * 2) * 262144 + lane * 8;
  auto bload = [&](int l, int g, int ks, int nt) -> half8 {
    return *(const half8*)(bptr + l * 262144
                           + (((2 * w + nt) * 32) + (g * 4 + ks)) * 512);
  };

  // ---- stage A tile once: 64 rows x 512 cols f32 -> f16 swizzled chunks ----
  {
    const int row = tid >> 3;            // 0..63
    const int cg  = tid & 7;             // 8 col-groups of 8 f32
    const int sw  = ((cg * 16) ^ ((row & 7) << 4));
    const float* hr = hidden + (size_t)(r0 + row) * DH + cg * 8;
    unsigned char* dst = smem + row * 128 + sw;
#pragma unroll
    for (int kc = 0; kc < 8; ++kc) {
      floatx4 u0 = *(const floatx4*)(hr + kc * 64);
      floatx4 u1 = *(const floatx4*)(hr + kc * 64 + 4);
      half8 p;
      p[0] = (f16)u0[0]; p[1] = (f16)u0[1]; p[2] = (f16)u0[2]; p[3] = (f16)u0[3];
      p[4] = (f16)u1[0]; p[5] = (f16)u1[1]; p[6] = (f16)u1[2]; p[7] = (f16)u1[3];
      *(half8*)(dst + kc * 8192) = p;
    }
  }

  floatx16 acc[2][2];
  const half8 hz = {(f16)0, (f16)0, (f16)0, (f16)0, (f16)0, (f16)0, (f16)0, (f16)0};

  __syncthreads();   // B1: A tile ready

  // ================= layer 1: h1 = relu(A @ w1^T + b1) — barrier-free ======
#pragma unroll
  for (int mt = 0; mt < 2; ++mt)
#pragma unroll
    for (int nt = 0; nt < 2; ++nt)
#pragma unroll
      for (int e = 0; e < 16; ++e) acc[mt][nt][e] = 0.f;

  {
    half8 bc[2][2], bn[2][2];
#pragma unroll
    for (int nt = 0; nt < 2; ++nt) {
      bc[nt][0] = bload(0, 0, 0, nt);
      bc[nt][1] = bload(0, 0, 1, nt);
    }
#pragma unroll 1
    for (int g = 0; g < 8; ++g) {
      // prefetch pair 1 (ks 2,3) of this chunk
#pragma unroll
      for (int nt = 0; nt < 2; ++nt) {
        bn[nt][0] = bload(0, g, 2, nt);
        bn[nt][1] = bload(0, g, 3, nt);
      }
      __builtin_amdgcn_s_setprio(1);
#pragma unroll
      for (int ks = 0; ks < 2; ++ks)
#pragma unroll
        for (int mt = 0; mt < 2; ++mt) {
          half8 a = aread32(g, mt, ks);
          acc[mt][0] = __builtin_amdgcn_mfma_f32_32x32x16_f16(a, bc[0][ks], acc[mt][0], 0, 0, 0);
          acc[mt][1] = __builtin_amdgcn_mfma_f32_32x32x16_f16(a, bc[1][ks], acc[mt][1], 0, 0, 0);
        }
      __builtin_amdgcn_s_setprio(0);
      // prefetch next chunk's pair 0
      if (g < 7) {
#pragma unroll
        for (int nt = 0; nt < 2; ++nt) {
          bc[nt][0] = bload(0, g + 1, 0, nt);
          bc[nt][1] = bload(0, g + 1, 1, nt);
        }
      }
      __builtin_amdgcn_s_setprio(1);
#pragma unroll
      for (int ks = 0; ks < 2; ++ks)
#pragma unroll
        for (int mt = 0; mt < 2; ++mt) {
          half8 a = aread32(g, mt, 2 + ks);
          acc[mt][0] = __builtin_amdgcn_mfma_f32_32x32x16_f16(a, bn[0][ks], acc[mt][0], 0, 0, 0);
          acc[mt][1] = __builtin_amdgcn_mfma_f32_32x32x16_f16(a, bn[1][ks], acc[mt][1], 0, 0, 0);
        }
      __builtin_amdgcn_s_setprio(0);
    }
  }

  __syncthreads();   // B2: all waves done READING A -> safe to overwrite

  // h1 epilogue: bias+relu -> wave's col chunk (chunk index w) of same region
  {
    unsigned char* myc = smem + w * 8192;
#pragma unroll
    for (int nt = 0; nt < 2; ++nt) {
      const float bv = b1g[m * DH + w * 64 + nt * 32 + l31];
      const int cb = 2 * (nt * 32 + l31);
#pragma unroll
      for (int mt = 0; mt < 2; ++mt)
#pragma unroll
        for (int e = 0; e < 16; ++e) {
          float v = fmaxf(acc[mt][nt][e] + bv, 0.f);
          int row = mt * 32 + (e & 3) + 8 * (e >> 2) + 4 * hi;
          *(f16*)(myc + row * 128 + (cb ^ ((row & 7) << 4))) = (f16)v;
        }
    }
  }
  __syncthreads();   // B3: h1 ready

  // ================= layer 2 (barrier-free) =================
#pragma unroll
  for (int mt = 0; mt < 2; ++mt)
#pragma unroll
    for (int nt = 0; nt < 2; ++nt)
#pragma unroll
      for (int e = 0; e < 16; ++e) acc[mt][nt][e] = 0.f;

  {
    half8 bc[2][2], bn[2][2];
#pragma unroll
    for (int nt = 0; nt < 2; ++nt) {
      bc[nt][0] = bload(1, 0, 0, nt);
      bc[nt][1] = bload(1, 0, 1, nt);
    }
#pragma unroll 1
    for (int g = 0; g < 8; ++g) {
#pragma unroll
      for (int nt = 0; nt < 2; ++nt) {
        bn[nt][0] = bload(1, g, 2, nt);
        bn[nt][1] = bload(1, g, 3, nt);
      }
      __builtin_amdgcn_s_setprio(1);
#pragma unroll
      for (int ks = 0; ks < 2; ++ks)
#pragma unroll
        for (int mt = 0; mt < 2; ++mt) {
          half8 a = aread32(g, mt, ks);
          acc[mt][0] = __builtin_amdgcn_mfma_f32_32x32x16_f16(a, bc[0][ks], acc[mt][0], 0, 0, 0);
          acc[mt][1] = __builtin_amdgcn_mfma_f32_32x32x16_f16(a, bc[1][ks], acc[mt][1], 0, 0, 0);
        }
      __builtin_amdgcn_s_setprio(0);
      if (g < 7) {
#pragma unroll
        for (int nt = 0; nt < 2; ++nt) {
          bc[nt][0] = bload(1, g + 1, 0, nt);
          bc[nt][1] = bload(1, g + 1, 1, nt);
        }
      }
      __builtin_amdgcn_s_setprio(1);
#pragma unroll
      for (int ks = 0; ks < 2; ++ks)
#pragma unroll
        for (int mt = 0; mt < 2; ++mt) {
          half8 a = aread32(g, mt, 2 + ks);
          acc[mt][0] = __builtin_amdgcn_mfma_f32_32x32x16_f16(a, bn[0][ks], acc[mt][0], 0, 0, 0);
          acc[mt][1] = __builtin_amdgcn_mfma_f32_32x32x16_f16(a, bn[1][ks], acc[mt][1], 0, 0, 0);
        }
      __builtin_amdgcn_s_setprio(0);
    }
  }

  __syncthreads();   // B4: all waves done reading h1 -> safe to overwrite

  // h2 -> same chunks
  {
    unsigned char* myc = smem + w * 8192;
#pragma unroll
    for (int nt = 0; nt < 2; ++nt) {
      const float bv = b2g[m * DH + w * 64 + nt * 32 + l31];
      const int cb = 2 * (nt * 32 + l31);
#pragma unroll
      for (int mt = 0; mt < 2; ++mt)
#pragma unroll
        for (int e = 0; e < 16; ++e) {
          float v = fmaxf(acc[mt][nt][e] + bv, 0.f);
          int row = mt * 32 + (e & 3) + 8 * (e >> 2) + 4 * hi;
          *(f16*)(myc + row * 128 + (cb ^ ((row & 7) << 4))) = (f16)v;
        }
    }
  }
  __syncthreads();   // B5: h2 ready

  // ---------------- head GEMM: waves 0..3, wave w -> rows 16w..16w+15 ----
  if (w < 4) {
    const int base_m = (m == 0) ? 0 : (m == 1) ? 1 : (m == 2) ? 7 : 11;
    const int cnt_m  = (m == 0) ? 1 : (m == 1) ? 6 : (m == 2) ? 4 : 12;
    const bool ovalid = l15 < cnt_m;
    const f16* w3row = w3f16 + (size_t)(base_m + (ovalid ? l15 : 0)) * DH;
    floatx4 acc3 = {0.f, 0.f, 0.f, 0.f};
#pragma unroll 2
    for (int q = 0; q < 16; ++q) {
      half8 ah = aread16(q, w);
      half8 wv = ovalid ? *(const half8*)(w3row + q * 32 + lg * 8) : hz;
      acc3 = __builtin_amdgcn_mfma_f32_16x16x32_f16(ah, wv, acc3, 0, 0, 0);
    }
    if (ovalid) {
      const float bo = b3g[base_m + l15];
#pragma unroll
      for (int j = 0; j < 4; ++j) {
        const int row = r0 + w * 16 + 4 * lg + j;
        const float v = acc3[j] + bo;
        if (m == 0)      { if (l15 == 0) dout[row] = v; }
        else if (m == 1) { dout[KROWS + row * 18 + (l15 < 3 ? l15 : l15 + 6)] = v; }
        else if (m == 2) { pred2d[row * 4 + l15] = v; }
        else             { dout[KROWS + row * 18 + (l15 < 6 ? l15 + 3 : l15 + 6)] = v; }
      }
    }
  }
}

// ---------------------------------------------------------------------------
// Loss math helpers (scalar fp32, matches jnp reference)
// ---------------------------------------------------------------------------
__device__ __forceinline__ void safe_norm3(float x, float y, float z, float* o) {
  float n = sqrtf(x * x + y * y + z * z);
  if (n > 1e-6f) { o[0] = x / n; o[1] = y / n; o[2] = z / n; }
  else           { o[0] = 1.f;   o[1] = 0.f;   o[2] = 0.f; }
}

__device__ __forceinline__ void rot6d(const float* x, float* R) {
  float a1[3]; safe_norm3(x[0], x[1], x[2], a1);
  float d = a1[0] * x[3] + a1[1] * x[4] + a1[2] * x[5];
  float b2[3]; safe_norm3(x[3] - d * a1[0], x[4] - d * a1[1], x[5] - d * a1[2], b2);
  float a3[3];
  safe_norm3(a1[1] * b2[2] - a1[2] * b2[1],
             a1[2] * b2[0] - a1[0] * b2[2],
             a1[0] * b2[1] - a1[1] * b2[0], a3);
  float bb[3];
  safe_norm3(a3[1] * a1[2] - a3[2] * a1[1],
             a3[2] * a1[0] - a3[0] * a1[2],
             a3[0] * a1[1] - a3[1] * a1[0], bb);
  R[0] = a1[0]; R[1] = a1[1]; R[2] = a1[2];
  R[3] = bb[0]; R[4] = bb[1]; R[5] = bb[2];
  R[6] = a3[0]; R[7] = a3[1]; R[8] = a3[2];
}

__device__ __forceinline__ float geo_angle(const float* P, const float* G) {
  float M[9];
#pragma unroll
  for (int i = 0; i < 3; ++i)
#pragma unroll
    for (int l = 0; l < 3; ++l)
      M[i * 3 + l] = G[0 + i] * P[0 + l] + G[3 + i] * P[3 + l] + G[6 + i] * P[6 + l];
  float tr = M[0] + M[4] + M[8];
  float c = fminf(fmaxf((tr - 1.f) * 0.5f, -1.f + 1e-6f), 1.f - 1e-6f);
  float v0 = M[7] - M[5], v1 = M[2] - M[6], v2 = M[3] - M[1];
  float s = 0.5f * sqrtf(v0 * v0 + v1 * v1 + v2 * v2) + 1e-8f;
  return atan2f(s, c);
}

// accumulators: 0 t_num 1 t_den 2 tv_sum 3..6 n3T d3T n3F d3F
//               7..10 n2T d2T n2F d2F  11..14 nqT dqT nqF dqF  15 rot_num 16 rot_den
__global__ __launch_bounds__(256) void loss_partial(
    const float* __restrict__ gt, const float* __restrict__ dout,
    const float* __restrict__ pred2d, float* __restrict__ partials)
{
  const int r = blockIdx.x * 256 + threadIdx.x;
  const float* g  = gt + (size_t)r * 23;
  const float* pk = dout + KROWS + (size_t)r * 18;
  float a[17];

  const float pt = dout[r];
  const float tg = g[0];
  const float tv = (tg != -1000.f) ? 1.f : 0.f;
  const float dt = fabsf(pt - tg);
  a[0] = ((dt < 3.f) ? (0.5f * dt * dt / 3.f) : (dt - 1.5f)) * tv;
  a[1] = tv;
  a[2] = tv;
  const float wt = expf(-0.5f * (dt / 3.f) * (dt / 3.f)) * tv;

  float n3T = 0.f, d3T = 0.f, n3F = 0.f, d3F = 0.f;
#pragma unroll
  for (int j = 0; j < 6; ++j) {
    const float p = pk[j < 3 ? j : j + 6];
    const float q = g[1 + j];
    const float val = (q != -1000.f) ? 1.f : 0.f;
    const float d = fabsf(p - q);
    const float l = (d < 0.07f) ? (0.5f * d * d / 0.07f) : (d - 0.035f);
    n3T += l * val * wt; d3T += val * wt; n3F += l * val; d3F += val;
  }
  a[3] = n3T; a[4] = d3T; a[5] = n3F; a[6] = d3F;

  float n2T = 0.f, d2T = 0.f, n2F = 0.f, d2F = 0.f;
#pragma unroll
  for (int j = 0; j < 4; ++j) {
    const float p = pred2d[(size_t)r * 4 + j];
    const float q = g[7 + j];
    const float val = (q != -1000.f) ? 1.f : 0.f;
    const float d = fabsf(p / 1408.f - q / 1408.f);
    const float l = (d < 0.02f) ? (0.5f * d * d / 0.02f) : (d - 0.01f);
    n2T += l * val * wt; d2T += val * wt; n2F += l * val; d2F += val;
  }
  a[7] = n2T; a[8] = d2T; a[9] = n2F; a[10] = d2F;

  float qp[12];
#pragma unroll
  for (int j = 0; j < 12; ++j) qp[j] = pk[j < 6 ? j + 3 : j + 6];
  float nqT = 0.f, dqT = 0.f, nqF = 0.f, dqF = 0.f;
#pragma unroll
  for (int j = 0; j < 12; ++j) {
    const float q = g[11 + j];
    const float val = (q != -1000.f) ? 1.f : 0.f;
    const float d = fabsf(qp[j] - q);
    const float l = (d < 0.2f) ? (0.5f * d * d / 0.2f) : (d - 0.1f);
    nqT += l * val * wt; dqT += val * wt; nqF += l * val; dqF += val;
  }
  a[11] = nqT; a[12] = dqT; a[13] = nqF; a[14] = dqF;

  bool Lv = true, Rv = true;
#pragma unroll
  for (int j = 0; j < 6; ++j) {
    if (g[11 + j] == -1000.f) Lv = false;
    if (g[17 + j] == -1000.f) Rv = false;
  }
  const float safe6[6] = {1.f, 0.f, 0.f, 0.f, 1.f, 0.f};
  float Lt[6], Rt[6];
#pragma unroll
  for (int j = 0; j < 6; ++j) {
    Lt[j] = Lv ? g[11 + j] : safe6[j];
    Rt[j] = Rv ? g[17 + j] : safe6[j];
  }
  float Rp[9], Rg[9];
  rot6d(qp, Rp);     rot6d(Lt, Rg);
  const float angL = geo_angle(Rp, Rg);
  rot6d(qp + 6, Rp); rot6d(Rt, Rg);
  const float angR = geo_angle(Rp, Rg);
  a[15] = (Lv ? angL : 0.f) + (Rv ? angR : 0.f);
  a[16] = (Lv ? 1.f : 0.f) + (Rv ? 1.f : 0.f);

#pragma unroll
  for (int i = 0; i < 17; ++i) {
    float v = a[i];
#pragma unroll
    for (int off = 32; off > 0; off >>= 1) v += __shfl_down(v, off, 64);
    a[i] = v;
  }
  __shared__ float red[4][17];
  if ((threadIdx.x & 63) == 0) {
    const int wv = threadIdx.x >> 6;
#pragma unroll
    for (int i = 0; i < 17; ++i) red[wv][i] = a[i];
  }
  __syncthreads();
  if (threadIdx.x < 17)
    partials[blockIdx.x * 20 + threadIdx.x] =
        red[0][threadIdx.x] + red[1][threadIdx.x] + red[2][threadIdx.x] + red[3][threadIdx.x];
}

__global__ void loss_final(const float* __restrict__ partials, float* __restrict__ dout)
{
  __shared__ float s[17];
  const int i = threadIdx.x;
  if (i < 17) {
    float v = 0.f;
    for (int b = 0; b < 256; ++b) v += partials[b * 20 + i];
    s[i] = v;
  }
  __syncthreads();
  if (i == 0) {
    const bool flag = s[2] > 0.f;
    const float time_loss = s[0] / fmaxf(s[1], 1.f);
    const float l3 = flag ? s[3] / fmaxf(s[4], 1.f) : s[5] / fmaxf(s[6], 1.f);
    const float l2 = flag ? s[7] / fmaxf(s[8], 1.f) : s[9] / fmaxf(s[10], 1.f);
    const float lq = flag ? s[11] / fmaxf(s[12], 1.f) : s[13] / fmaxf(s[14], 1.f);
    const float rot = 0.15f * (s[15] / fmaxf(s[16], 1e-8f));
    dout[19 * KROWS] = time_loss + 2.f * l3 + 0.5f * l2 + 0.5f * lq + rot;
  }
}

// ---------------------------------------------------------------------------
extern "C" void kernel_launch(void* const* d_in, const int* in_sizes, int n_in,
                              void* d_out, int out_size, void* d_ws, size_t ws_size,
                              hipStream_t stream) {
  (void)in_sizes; (void)n_in; (void)out_size; (void)ws_size;
  const float* hidden = (const float*)d_in[0];
  const float* gt     = (const float*)d_in[1];
  const float* w1     = (const float*)d_in[2];
  const float* b1     = (const float*)d_in[3];
  const float* w2     = (const float*)d_in[4];
  const float* b2     = (const float*)d_in[5];
  const float* w3     = (const float*)d_in[6];
  const float* b3     = (const float*)d_in[7];
  float* dout = (float*)d_out;

  unsigned char* ws = (unsigned char*)d_ws;
  f16*   wf16     = (f16*)(ws + WS_WF16);
  f16*   w3f16    = (f16*)(ws + WS_W3F16);
  float* pred2d   = (float*)(ws + WS_PRED2D);
  float* partials = (float*)(ws + WS_PART);

  convert_weights<<<1070, 256, 0, stream>>>(w1, w2, w3, wf16, w3f16);
  fused_kernel<<<4096, 512, 0, stream>>>(hidden, wf16, w3f16, b1, b2, b3, dout, pred2d);
  loss_partial<<<256, 256, 0, stream>>>(gt, dout, pred2d, partials);
  loss_final<<<1, 64, 0, stream>>>(partials, dout);
}

// Round 17
// 356.224 us; speedup vs baseline: 1.0339x; 1.0339x over previous
//
#include <hip/hip_runtime.h>
#include <math.h>

// TrajDecoder on MI355X (gfx950).  Round 17: REVERT to R15 (measured optimum).
//   R16's ks-pair prefetch re-spilled (WRITE 84->297MB) and regressed; all
//   pipelining avenues are now measured dead ends under the 128-reg budget:
//   reg-prefetch -> spill (R10/R14/R16), A-from-global -> latency (R12),
//   B-via-LDS -> LDS-port bound (R1-R3), low-occupancy -> TLP loss (R9/R10),
//   small tiles -> intensity loss (R11/R13).  R15 structure: 32x32x16 MFMA,
//   staged-once A in 64KB static LDS reused for h1/h2 (5 barriers), B
//   frag-packed direct from global/L2 (head->XCD pinned), 2 blocks/CU.

#define KROWS 65536
#define DH 512

typedef _Float16 f16;
typedef _Float16 half8 __attribute__((ext_vector_type(8)));
typedef float floatx4 __attribute__((ext_vector_type(4)));
typedef float floatx16 __attribute__((ext_vector_type(16)));

#define WS_WF16   0
#define WS_W3F16  4194304
#define WS_PRED2D 4227072
#define WS_PART   5275648

// ---------------------------------------------------------------------------
// Weight conversion, 32x32 frag-packed layout:
//   region (m,l): 512KB at ml*262144 f16.  frag-block fb = nt32*32 + ks (1KB),
//   lane slot holds w[nt32*32 + (lane&31)][ks*16 + (lane>>5)*8 .. +8].
// ---------------------------------------------------------------------------
__global__ __launch_bounds__(256) void convert_weights(
    const float* __restrict__ w1, const float* __restrict__ w2,
    const float* __restrict__ w3, f16* __restrict__ wf16, f16* __restrict__ w3f16)
{
  int t = blockIdx.x * 256 + threadIdx.x;
  if (t < 262144) {
    int ml = t >> 15;              // (m,l) 0..7
    int mm = ml >> 1, l = ml & 1;
    int r = t & 32767;
    int fb = r >> 6;               // nt32*32 + ks, 0..511
    int lane = r & 63;
    int nt = fb >> 5, ks = fb & 31;
    int n = nt * 32 + (lane & 31);
    int k = ks * 16 + (lane >> 5) * 8;
    const float* src = (l ? w2 : w1) + (size_t)mm * 262144 + n * 512 + k;
    floatx4 u0 = *(const floatx4*)(src);
    floatx4 u1 = *(const floatx4*)(src + 4);
    half8 h;
    h[0] = (f16)u0[0]; h[1] = (f16)u0[1]; h[2] = (f16)u0[2]; h[3] = (f16)u0[3];
    h[4] = (f16)u1[0]; h[5] = (f16)u1[1]; h[6] = (f16)u1[2]; h[7] = (f16)u1[3];
    *(half8*)(wf16 + (size_t)ml * 262144 + fb * 512 + lane * 8) = h;
  } else {
    int j = t - 262144;
    if (j < 23 * DH) w3f16[j] = (f16)w3[j];
  }
}

// ---------------------------------------------------------------------------
// Fused 2-layer MLP + head.  grid = 4096 x 512 (8 waves).  Wave tile 64x64
// as 2x2 fragments of 32x32.  One head per block (head -> XCD pinning).
// LDS (STATIC 64KB): one region, 8 chunks of [64r x 64c] f16 swizzled;
//   lifecycle A -> h1 -> h2.  Swizzle: byte row*128 + (2c ^ ((row&7)<<4)).
// ---------------------------------------------------------------------------
__global__ __launch_bounds__(512, 4)
__attribute__((amdgpu_waves_per_eu(4, 4)))
void fused_kernel(
    const float* __restrict__ hidden,
    const f16* __restrict__ wf16,
    const f16* __restrict__ w3f16,
    const float* __restrict__ b1g,
    const float* __restrict__ b2g,
    const float* __restrict__ b3g,
    float* __restrict__ dout,
    float* __restrict__ pred2d)
{
  __shared__ __align__(16) unsigned char smem[65536];

  const int bid = blockIdx.x;
  const int rr  = bid & 7;
  const int m   = rr >> 1;                            // head -> XCD pair
  const int row_tile = ((bid >> 3) << 1) | (rr & 1);  // 0..1023
  const int r0  = row_tile * 64;
  const int tid = threadIdx.x;
  const int w   = __builtin_amdgcn_readfirstlane(tid >> 6);  // SGPR wave idx
  const int lane = tid & 63;
  const int l15 = lane & 15;
  const int lg  = lane >> 4;
  const int l31 = lane & 31;
  const int hi  = lane >> 5;

  // --- 32x32 A-frag read offsets (rows mt*32+l31, k = ks*16 + hi*8) ---
  const int arow32 = l31 * 128;
  const int hi16   = hi * 16;
  const int sw31   = (lane & 7) << 4;   // (row&7)<<4, row = mt*32+l31
  auto aread32 = [&](int g, int mt, int ks) -> half8 {
    return *(const half8*)(smem + g * 8192 + mt * 4096 + arow32
                           + ((ks * 32 + hi16) ^ sw31));
  };
  // --- 16x16 A-frag read (head GEMM path; rows 16-based) ---
  const int arow16 = l15 * 128;
  const int ao16   = (lg * 16) ^ ((l15 & 7) << 4);
  auto aread16 = [&](int q, int mt) -> half8 {
    return *(const half8*)(smem + (q >> 1) * 8192 + mt * 2048 + arow16
                           + (ao16 ^ ((q & 1) << 6)));
  };
  // --- B-frag (layer l, chunk g in [0,8), k-step ks in [0,4), nt in [0,2)) ---
  const f16* bptr = wf16 + (size_t)(m * 2) * 262144 + lane * 8;
  auto bload = [&](int l, int g, int ks, int nt) -> half8 {
    return *(const half8*)(bptr + l * 262144
                           + (((2 * w + nt) * 32) + (g * 4 + ks)) * 512);
  };

  // ---- stage A tile once: 64 rows x 512 cols f32 -> f16 swizzled chunks ----
  {
    const int row = tid >> 3;            // 0..63
    const int cg  = tid & 7;             // 8 col-groups of 8 f32
    const int sw  = ((cg * 16) ^ ((row & 7) << 4));
    const float* hr = hidden + (size_t)(r0 + row) * DH + cg * 8;
    unsigned char* dst = smem + row * 128 + sw;
#pragma unroll
    for (int kc = 0; kc < 8; ++kc) {
      floatx4 u0 = *(const floatx4*)(hr + kc * 64);
      floatx4 u1 = *(const floatx4*)(hr + kc * 64 + 4);
      half8 p;
      p[0] = (f16)u0[0]; p[1] = (f16)u0[1]; p[2] = (f16)u0[2]; p[3] = (f16)u0[3];
      p[4] = (f16)u1[0]; p[5] = (f16)u1[1]; p[6] = (f16)u1[2]; p[7] = (f16)u1[3];
      *(half8*)(dst + kc * 8192) = p;
    }
  }

  floatx16 acc[2][2];
  const half8 hz = {(f16)0, (f16)0, (f16)0, (f16)0, (f16)0, (f16)0, (f16)0, (f16)0};

  __syncthreads();   // B1: A tile ready

  // ================= layer 1: h1 = relu(A @ w1^T + b1) — barrier-free ======
#pragma unroll
  for (int mt = 0; mt < 2; ++mt)
#pragma unroll
    for (int nt = 0; nt < 2; ++nt)
#pragma unroll
      for (int e = 0; e < 16; ++e) acc[mt][nt][e] = 0.f;

#pragma unroll 1
  for (int g = 0; g < 8; ++g) {
    half8 b[2][4];
#pragma unroll
    for (int nt = 0; nt < 2; ++nt)
#pragma unroll
      for (int ks = 0; ks < 4; ++ks) b[nt][ks] = bload(0, g, ks, nt);
#pragma unroll
    for (int ks = 0; ks < 4; ++ks) {
#pragma unroll
      for (int mt = 0; mt < 2; ++mt) {
        half8 a = aread32(g, mt, ks);
        acc[mt][0] = __builtin_amdgcn_mfma_f32_32x32x16_f16(a, b[0][ks], acc[mt][0], 0, 0, 0);
        acc[mt][1] = __builtin_amdgcn_mfma_f32_32x32x16_f16(a, b[1][ks], acc[mt][1], 0, 0, 0);
      }
    }
  }

  __syncthreads();   // B2: all waves done READING A -> safe to overwrite

  // h1 epilogue: bias+relu -> wave's col chunk (chunk index w) of same region
  {
    unsigned char* myc = smem + w * 8192;
#pragma unroll
    for (int nt = 0; nt < 2; ++nt) {
      const float bv = b1g[m * DH + w * 64 + nt * 32 + l31];
      const int cb = 2 * (nt * 32 + l31);
#pragma unroll
      for (int mt = 0; mt < 2; ++mt)
#pragma unroll
        for (int e = 0; e < 16; ++e) {
          float v = fmaxf(acc[mt][nt][e] + bv, 0.f);
          int row = mt * 32 + (e & 3) + 8 * (e >> 2) + 4 * hi;
          *(f16*)(myc + row * 128 + (cb ^ ((row & 7) << 4))) = (f16)v;
        }
    }
  }
  __syncthreads();   // B3: h1 ready

  // ================= layer 2 (barrier-free) =================
#pragma unroll
  for (int mt = 0; mt < 2; ++mt)
#pragma unroll
    for (int nt = 0; nt < 2; ++nt)
#pragma unroll
      for (int e = 0; e < 16; ++e) acc[mt][nt][e] = 0.f;

#pragma unroll 1
  for (int g = 0; g < 8; ++g) {
    half8 b[2][4];
#pragma unroll
    for (int nt = 0; nt < 2; ++nt)
#pragma unroll
      for (int ks = 0; ks < 4; ++ks) b[nt][ks] = bload(1, g, ks, nt);
#pragma unroll
    for (int ks = 0; ks < 4; ++ks) {
#pragma unroll
      for (int mt = 0; mt < 2; ++mt) {
        half8 a = aread32(g, mt, ks);
        acc[mt][0] = __builtin_amdgcn_mfma_f32_32x32x16_f16(a, b[0][ks], acc[mt][0], 0, 0, 0);
        acc[mt][1] = __builtin_amdgcn_mfma_f32_32x32x16_f16(a, b[1][ks], acc[mt][1], 0, 0, 0);
      }
    }
  }

  __syncthreads();   // B4: all waves done reading h1 -> safe to overwrite

  // h2 -> same chunks
  {
    unsigned char* myc = smem + w * 8192;
#pragma unroll
    for (int nt = 0; nt < 2; ++nt) {
      const float bv = b2g[m * DH + w * 64 + nt * 32 + l31];
      const int cb = 2 * (nt * 32 + l31);
#pragma unroll
      for (int mt = 0; mt < 2; ++mt)
#pragma unroll
        for (int e = 0; e < 16; ++e) {
          float v = fmaxf(acc[mt][nt][e] + bv, 0.f);
          int row = mt * 32 + (e & 3) + 8 * (e >> 2) + 4 * hi;
          *(f16*)(myc + row * 128 + (cb ^ ((row & 7) << 4))) = (f16)v;
        }
    }
  }
  __syncthreads();   // B5: h2 ready

  // ---------------- head GEMM: waves 0..3, wave w -> rows 16w..16w+15 ----
  if (w < 4) {
    const int base_m = (m == 0) ? 0 : (m == 1) ? 1 : (m == 2) ? 7 : 11;
    const int cnt_m  = (m == 0) ? 1 : (m == 1) ? 6 : (m == 2) ? 4 : 12;
    const bool ovalid = l15 < cnt_m;
    const f16* w3row = w3f16 + (size_t)(base_m + (ovalid ? l15 : 0)) * DH;
    floatx4 acc3 = {0.f, 0.f, 0.f, 0.f};
#pragma unroll 2
    for (int q = 0; q < 16; ++q) {
      half8 ah = aread16(q, w);
      half8 wv = ovalid ? *(const half8*)(w3row + q * 32 + lg * 8) : hz;
      acc3 = __builtin_amdgcn_mfma_f32_16x16x32_f16(ah, wv, acc3, 0, 0, 0);
    }
    if (ovalid) {
      const float bo = b3g[base_m + l15];
#pragma unroll
      for (int j = 0; j < 4; ++j) {
        const int row = r0 + w * 16 + 4 * lg + j;
        const float v = acc3[j] + bo;
        if (m == 0)      { if (l15 == 0) dout[row] = v; }
        else if (m == 1) { dout[KROWS + row * 18 + (l15 < 3 ? l15 : l15 + 6)] = v; }
        else if (m == 2) { pred2d[row * 4 + l15] = v; }
        else             { dout[KROWS + row * 18 + (l15 < 6 ? l15 + 3 : l15 + 6)] = v; }
      }
    }
  }
}

// ---------------------------------------------------------------------------
// Loss math helpers (scalar fp32, matches jnp reference)
// ---------------------------------------------------------------------------
__device__ __forceinline__ void safe_norm3(float x, float y, float z, float* o) {
  float n = sqrtf(x * x + y * y + z * z);
  if (n > 1e-6f) { o[0] = x / n; o[1] = y / n; o[2] = z / n; }
  else           { o[0] = 1.f;   o[1] = 0.f;   o[2] = 0.f; }
}

__device__ __forceinline__ void rot6d(const float* x, float* R) {
  float a1[3]; safe_norm3(x[0], x[1], x[2], a1);
  float d = a1[0] * x[3] + a1[1] * x[4] + a1[2] * x[5];
  float b2[3]; safe_norm3(x[3] - d * a1[0], x[4] - d * a1[1], x[5] - d * a1[2], b2);
  float a3[3];
  safe_norm3(a1[1] * b2[2] - a1[2] * b2[1],
             a1[2] * b2[0] - a1[0] * b2[2],
             a1[0] * b2[1] - a1[1] * b2[0], a3);
  float bb[3];
  safe_norm3(a3[1] * a1[2] - a3[2] * a1[1],
             a3[2] * a1[0] - a3[0] * a1[2],
             a3[0] * a1[1] - a3[1] * a1[0], bb);
  R[0] = a1[0]; R[1] = a1[1]; R[2] = a1[2];
  R[3] = bb[0]; R[4] = bb[1]; R[5] = bb[2];
  R[6] = a3[0]; R[7] = a3[1]; R[8] = a3[2];
}

__device__ __forceinline__ float geo_angle(const float* P, const float* G) {
  float M[9];
#pragma unroll
  for (int i = 0; i < 3; ++i)
#pragma unroll
    for (int l = 0; l < 3; ++l)
      M[i * 3 + l] = G[0 + i] * P[0 + l] + G[3 + i] * P[3 + l] + G[6 + i] * P[6 + l];
  float tr = M[0] + M[4] + M[8];
  float c = fminf(fmaxf((tr - 1.f) * 0.5f, -1.f + 1e-6f), 1.f - 1e-6f);
  float v0 = M[7] - M[5], v1 = M[2] - M[6], v2 = M[3] - M[1];
  float s = 0.5f * sqrtf(v0 * v0 + v1 * v1 + v2 * v2) + 1e-8f;
  return atan2f(s, c);
}

// accumulators: 0 t_num 1 t_den 2 tv_sum 3..6 n3T d3T n3F d3F
//               7..10 n2T d2T n2F d2F  11..14 nqT dqT nqF dqF  15 rot_num 16 rot_den
__global__ __launch_bounds__(256) void loss_partial(
    const float* __restrict__ gt, const float* __restrict__ dout,
    const float* __restrict__ pred2d, float* __restrict__ partials)
{
  const int r = blockIdx.x * 256 + threadIdx.x;
  const float* g  = gt + (size_t)r * 23;
  const float* pk = dout + KROWS + (size_t)r * 18;
  float a[17];

  const float pt = dout[r];
  const float tg = g[0];
  const float tv = (tg != -1000.f) ? 1.f : 0.f;
  const float dt = fabsf(pt - tg);
  a[0] = ((dt < 3.f) ? (0.5f * dt * dt / 3.f) : (dt - 1.5f)) * tv;
  a[1] = tv;
  a[2] = tv;
  const float wt = expf(-0.5f * (dt / 3.f) * (dt / 3.f)) * tv;

  float n3T = 0.f, d3T = 0.f, n3F = 0.f, d3F = 0.f;
#pragma unroll
  for (int j = 0; j < 6; ++j) {
    const float p = pk[j < 3 ? j : j + 6];
    const float q = g[1 + j];
    const float val = (q != -1000.f) ? 1.f : 0.f;
    const float d = fabsf(p - q);
    const float l = (d < 0.07f) ? (0.5f * d * d / 0.07f) : (d - 0.035f);
    n3T += l * val * wt; d3T += val * wt; n3F += l * val; d3F += val;
  }
  a[3] = n3T; a[4] = d3T; a[5] = n3F; a[6] = d3F;

  float n2T = 0.f, d2T = 0.f, n2F = 0.f, d2F = 0.f;
#pragma unroll
  for (int j = 0; j < 4; ++j) {
    const float p = pred2d[(size_t)r * 4 + j];
    const float q = g[7 + j];
    const float val = (q != -1000.f) ? 1.f : 0.f;
    const float d = fabsf(p / 1408.f - q / 1408.f);
    const float l = (d < 0.02f) ? (0.5f * d * d / 0.02f) : (d - 0.01f);
    n2T += l * val * wt; d2T += val * wt; n2F += l * val; d2F += val;
  }
  a[7] = n2T; a[8] = d2T; a[9] = n2F; a[10] = d2F;

  float qp[12];
#pragma unroll
  for (int j = 0; j < 12; ++j) qp[j] = pk[j < 6 ? j + 3 : j + 6];
  float nqT = 0.f, dqT = 0.f, nqF = 0.f, dqF = 0.f;
#pragma unroll
  for (int j = 0; j < 12; ++j) {
    const float q = g[11 + j];
    const float val = (q != -1000.f) ? 1.f : 0.f;
    const float d = fabsf(qp[j] - q);
    const float l = (d < 0.2f) ? (0.5f * d * d / 0.2f) : (d - 0.1f);
    nqT += l * val * wt; dqT += val * wt; nqF += l * val; dqF += val;
  }
  a[11] = nqT; a[12] = dqT; a[13] = nqF; a[14] = dqF;

  bool Lv = true, Rv = true;
#pragma unroll
  for (int j = 0; j < 6; ++j) {
    if (g[11 + j] == -1000.f) Lv = false;
    if (g[17 + j] == -1000.f) Rv = false;
  }
  const float safe6[6] = {1.f, 0.f, 0.f, 0.f, 1.f, 0.f};
  float Lt[6], Rt[6];
#pragma unroll
  for (int j = 0; j < 6; ++j) {
    Lt[j] = Lv ? g[11 + j] : safe6[j];
    Rt[j] = Rv ? g[17 + j] : safe6[j];
  }
  float Rp[9], Rg[9];
  rot6d(qp, Rp);     rot6d(Lt, Rg);
  const float angL = geo_angle(Rp, Rg);
  rot6d(qp + 6, Rp); rot6d(Rt, Rg);
  const float angR = geo_angle(Rp, Rg);
  a[15] = (Lv ? angL : 0.f) + (Rv ? angR : 0.f);
  a[16] = (Lv ? 1.f : 0.f) + (Rv ? 1.f : 0.f);

#pragma unroll
  for (int i = 0; i < 17; ++i) {
    float v = a[i];
#pragma unroll
    for (int off = 32; off > 0; off >>= 1) v += __shfl_down(v, off, 64);
    a[i] = v;
  }
  __shared__ float red[4][17];
  if ((threadIdx.x & 63) == 0) {
    const int wv = threadIdx.x >> 6;
#pragma unroll
    for (int i = 0; i < 17; ++i) red[wv][i] = a[i];
  }
  __syncthreads();
  if (threadIdx.x < 17)
    partials[blockIdx.x * 20 + threadIdx.x] =
        red[0][threadIdx.x] + red[1][threadIdx.x] + red[2][threadIdx.x] + red[3][threadIdx.x];
}

__global__ void loss_final(const float* __restrict__ partials, float* __restrict__ dout)
{
  __shared__ float s[17];
  const int i = threadIdx.x;
  if (i < 17) {
    float v = 0.f;
    for (int b = 0; b < 256; ++b) v += partials[b * 20 + i];
    s[i] = v;
  }
  __syncthreads();
  if (i == 0) {
    const bool flag = s[2] > 0.f;
    const float time_loss = s[0] / fmaxf(s[1], 1.f);
    const float l3 = flag ? s[3] / fmaxf(s[4], 1.f) : s[5] / fmaxf(s[6], 1.f);
    const float l2 = flag ? s[7] / fmaxf(s[8], 1.f) : s[9] / fmaxf(s[10], 1.f);
    const float lq = flag ? s[11] / fmaxf(s[12], 1.f) : s[13] / fmaxf(s[14], 1.f);
    const float rot = 0.15f * (s[15] / fmaxf(s[16], 1e-8f));
    dout[19 * KROWS] = time_loss + 2.f * l3 + 0.5f * l2 + 0.5f * lq + rot;
  }
}

// ---------------------------------------------------------------------------
extern "C" void kernel_launch(void* const* d_in, const int* in_sizes, int n_in,
                              void* d_out, int out_size, void* d_ws, size_t ws_size,
                              hipStream_t stream) {
  (void)in_sizes; (void)n_in; (void)out_size; (void)ws_size;
  const float* hidden = (const float*)d_in[0];
  const float* gt     = (const float*)d_in[1];
  const float* w1     = (const float*)d_in[2];
  const float* b1     = (const float*)d_in[3];
  const float* w2     = (const float*)d_in[4];
  const float* b2     = (const float*)d_in[5];
  const float* w3     = (const float*)d_in[6];
  const float* b3     = (const float*)d_in[7];
  float* dout = (float*)d_out;

  unsigned char* ws = (unsigned char*)d_ws;
  f16*   wf16     = (f16*)(ws + WS_WF16);
  f16*   w3f16    = (f16*)(ws + WS_W3F16);
  float* pred2d   = (float*)(ws + WS_PRED2D);
  float* partials = (float*)(ws + WS_PART);

  convert_weights<<<1070, 256, 0, stream>>>(w1, w2, w3, wf16, w3f16);
  fused_kernel<<<4096, 512, 0, stream>>>(hidden, wf16, w3f16, b1, b2, b3, dout, pred2d);
  loss_partial<<<256, 256, 0, stream>>>(gt, dout, pred2d, partials);
  loss_final<<<1, 64, 0, stream>>>(partials, dout);
}

// Round 18
// 350.327 us; speedup vs baseline: 1.0513x; 1.0168x over previous
//
#include <hip/hip_runtime.h>
#include <math.h>

// TrajDecoder on MI355X (gfx950).  Round 18: R15/R17 + setprio ONLY.
//   R16 bundled prefetch(+spill) with setprio; the spill masked setprio's
//   effect.  Setprio adds ZERO registers -> cannot spill.  Barrier-free GEMM
//   loops give natural wave phase-drift (T5's regime): MFMA-cluster waves
//   preempt load-issuing waves.  Everything else byte-identical to R17
//   (356us, MfmaUtil 35.3, WRITE 84MB): 32x32x16 MFMA, staged-once A in 64KB
//   static LDS reused for h1/h2, B frag-packed from global/L2, 2 blocks/CU.

#define KROWS 65536
#define DH 512

typedef _Float16 f16;
typedef _Float16 half8 __attribute__((ext_vector_type(8)));
typedef float floatx4 __attribute__((ext_vector_type(4)));
typedef float floatx16 __attribute__((ext_vector_type(16)));

#define WS_WF16   0
#define WS_W3F16  4194304
#define WS_PRED2D 4227072
#define WS_PART   5275648

// ---------------------------------------------------------------------------
// Weight conversion, 32x32 frag-packed layout:
//   region (m,l): 512KB at ml*262144 f16.  frag-block fb = nt32*32 + ks (1KB),
//   lane slot holds w[nt32*32 + (lane&31)][ks*16 + (lane>>5)*8 .. +8].
// ---------------------------------------------------------------------------
__global__ __launch_bounds__(256) void convert_weights(
    const float* __restrict__ w1, const float* __restrict__ w2,
    const float* __restrict__ w3, f16* __restrict__ wf16, f16* __restrict__ w3f16)
{
  int t = blockIdx.x * 256 + threadIdx.x;
  if (t < 262144) {
    int ml = t >> 15;              // (m,l) 0..7
    int mm = ml >> 1, l = ml & 1;
    int r = t & 32767;
    int fb = r >> 6;               // nt32*32 + ks, 0..511
    int lane = r & 63;
    int nt = fb >> 5, ks = fb & 31;
    int n = nt * 32 + (lane & 31);
    int k = ks * 16 + (lane >> 5) * 8;
    const float* src = (l ? w2 : w1) + (size_t)mm * 262144 + n * 512 + k;
    floatx4 u0 = *(const floatx4*)(src);
    floatx4 u1 = *(const floatx4*)(src + 4);
    half8 h;
    h[0] = (f16)u0[0]; h[1] = (f16)u0[1]; h[2] = (f16)u0[2]; h[3] = (f16)u0[3];
    h[4] = (f16)u1[0]; h[5] = (f16)u1[1]; h[6] = (f16)u1[2]; h[7] = (f16)u1[3];
    *(half8*)(wf16 + (size_t)ml * 262144 + fb * 512 + lane * 8) = h;
  } else {
    int j = t - 262144;
    if (j < 23 * DH) w3f16[j] = (f16)w3[j];
  }
}

// ---------------------------------------------------------------------------
// Fused 2-layer MLP + head.  grid = 4096 x 512 (8 waves).  Wave tile 64x64
// as 2x2 fragments of 32x32.  One head per block (head -> XCD pinning).
// LDS (STATIC 64KB): one region, 8 chunks of [64r x 64c] f16 swizzled;
//   lifecycle A -> h1 -> h2.  Swizzle: byte row*128 + (2c ^ ((row&7)<<4)).
// ---------------------------------------------------------------------------
__global__ __launch_bounds__(512, 4)
__attribute__((amdgpu_waves_per_eu(4, 4)))
void fused_kernel(
    const float* __restrict__ hidden,
    const f16* __restrict__ wf16,
    const f16* __restrict__ w3f16,
    const float* __restrict__ b1g,
    const float* __restrict__ b2g,
    const float* __restrict__ b3g,
    float* __restrict__ dout,
    float* __restrict__ pred2d)
{
  __shared__ __align__(16) unsigned char smem[65536];

  const int bid = blockIdx.x;
  const int rr  = bid & 7;
  const int m   = rr >> 1;                            // head -> XCD pair
  const int row_tile = ((bid >> 3) << 1) | (rr & 1);  // 0..1023
  const int r0  = row_tile * 64;
  const int tid = threadIdx.x;
  const int w   = __builtin_amdgcn_readfirstlane(tid >> 6);  // SGPR wave idx
  const int lane = tid & 63;
  const int l15 = lane & 15;
  const int lg  = lane >> 4;
  const int l31 = lane & 31;
  const int hi  = lane >> 5;

  // --- 32x32 A-frag read offsets (rows mt*32+l31, k = ks*16 + hi*8) ---
  const int arow32 = l31 * 128;
  const int hi16   = hi * 16;
  const int sw31   = (lane & 7) << 4;   // (row&7)<<4, row = mt*32+l31
  auto aread32 = [&](int g, int mt, int ks) -> half8 {
    return *(const half8*)(smem + g * 8192 + mt * 4096 + arow32
                           + ((ks * 32 + hi16) ^ sw31));
  };
  // --- 16x16 A-frag read (head GEMM path; rows 16-based) ---
  const int arow16 = l15 * 128;
  const int ao16   = (lg * 16) ^ ((l15 & 7) << 4);
  auto aread16 = [&](int q, int mt) -> half8 {
    return *(const half8*)(smem + (q >> 1) * 8192 + mt * 2048 + arow16
                           + (ao16 ^ ((q & 1) << 6)));
  };
  // --- B-frag (layer l, chunk g in [0,8), k-step ks in [0,4), nt in [0,2)) ---
  const f16* bptr = wf16 + (size_t)(m * 2) * 262144 + lane * 8;
  auto bload = [&](int l, int g, int ks, int nt) -> half8 {
    return *(const half8*)(bptr + l * 262144
                           + (((2 * w + nt) * 32) + (g * 4 + ks)) * 512);
  };

  // ---- stage A tile once: 64 rows x 512 cols f32 -> f16 swizzled chunks ----
  {
    const int row = tid >> 3;            // 0..63
    const int cg  = tid & 7;             // 8 col-groups of 8 f32
    const int sw  = ((cg * 16) ^ ((row & 7) << 4));
    const float* hr = hidden + (size_t)(r0 + row) * DH + cg * 8;
    unsigned char* dst = smem + row * 128 + sw;
#pragma unroll
    for (int kc = 0; kc < 8; ++kc) {
      floatx4 u0 = *(const floatx4*)(hr + kc * 64);
      floatx4 u1 = *(const floatx4*)(hr + kc * 64 + 4);
      half8 p;
      p[0] = (f16)u0[0]; p[1] = (f16)u0[1]; p[2] = (f16)u0[2]; p[3] = (f16)u0[3];
      p[4] = (f16)u1[0]; p[5] = (f16)u1[1]; p[6] = (f16)u1[2]; p[7] = (f16)u1[3];
      *(half8*)(dst + kc * 8192) = p;
    }
  }

  floatx16 acc[2][2];
  const half8 hz = {(f16)0, (f16)0, (f16)0, (f16)0, (f16)0, (f16)0, (f16)0, (f16)0};

  __syncthreads();   // B1: A tile ready

  // ================= layer 1: h1 = relu(A @ w1^T + b1) — barrier-free ======
#pragma unroll
  for (int mt = 0; mt < 2; ++mt)
#pragma unroll
    for (int nt = 0; nt < 2; ++nt)
#pragma unroll
      for (int e = 0; e < 16; ++e) acc[mt][nt][e] = 0.f;

#pragma unroll 1
  for (int g = 0; g < 8; ++g) {
    half8 b[2][4];
#pragma unroll
    for (int nt = 0; nt < 2; ++nt)
#pragma unroll
      for (int ks = 0; ks < 4; ++ks) b[nt][ks] = bload(0, g, ks, nt);
    __builtin_amdgcn_s_setprio(1);
#pragma unroll
    for (int ks = 0; ks < 4; ++ks) {
#pragma unroll
      for (int mt = 0; mt < 2; ++mt) {
        half8 a = aread32(g, mt, ks);
        acc[mt][0] = __builtin_amdgcn_mfma_f32_32x32x16_f16(a, b[0][ks], acc[mt][0], 0, 0, 0);
        acc[mt][1] = __builtin_amdgcn_mfma_f32_32x32x16_f16(a, b[1][ks], acc[mt][1], 0, 0, 0);
      }
    }
    __builtin_amdgcn_s_setprio(0);
  }

  __syncthreads();   // B2: all waves done READING A -> safe to overwrite

  // h1 epilogue: bias+relu -> wave's col chunk (chunk index w) of same region
  {
    unsigned char* myc = smem + w * 8192;
#pragma unroll
    for (int nt = 0; nt < 2; ++nt) {
      const float bv = b1g[m * DH + w * 64 + nt * 32 + l31];
      const int cb = 2 * (nt * 32 + l31);
#pragma unroll
      for (int mt = 0; mt < 2; ++mt)
#pragma unroll
        for (int e = 0; e < 16; ++e) {
          float v = fmaxf(acc[mt][nt][e] + bv, 0.f);
          int row = mt * 32 + (e & 3) + 8 * (e >> 2) + 4 * hi;
          *(f16*)(myc + row * 128 + (cb ^ ((row & 7) << 4))) = (f16)v;
        }
    }
  }
  __syncthreads();   // B3: h1 ready

  // ================= layer 2 (barrier-free) =================
#pragma unroll
  for (int mt = 0; mt < 2; ++mt)
#pragma unroll
    for (int nt = 0; nt < 2; ++nt)
#pragma unroll
      for (int e = 0; e < 16; ++e) acc[mt][nt][e] = 0.f;

#pragma unroll 1
  for (int g = 0; g < 8; ++g) {
    half8 b[2][4];
#pragma unroll
    for (int nt = 0; nt < 2; ++nt)
#pragma unroll
      for (int ks = 0; ks < 4; ++ks) b[nt][ks] = bload(1, g, ks, nt);
    __builtin_amdgcn_s_setprio(1);
#pragma unroll
    for (int ks = 0; ks < 4; ++ks) {
#pragma unroll
      for (int mt = 0; mt < 2; ++mt) {
        half8 a = aread32(g, mt, ks);
        acc[mt][0] = __builtin_amdgcn_mfma_f32_32x32x16_f16(a, b[0][ks], acc[mt][0], 0, 0, 0);
        acc[mt][1] = __builtin_amdgcn_mfma_f32_32x32x16_f16(a, b[1][ks], acc[mt][1], 0, 0, 0);
      }
    }
    __builtin_amdgcn_s_setprio(0);
  }

  __syncthreads();   // B4: all waves done reading h1 -> safe to overwrite

  // h2 -> same chunks
  {
    unsigned char* myc = smem + w * 8192;
#pragma unroll
    for (int nt = 0; nt < 2; ++nt) {
      const float bv = b2g[m * DH + w * 64 + nt * 32 + l31];
      const int cb = 2 * (nt * 32 + l31);
#pragma unroll
      for (int mt = 0; mt < 2; ++mt)
#pragma unroll
        for (int e = 0; e < 16; ++e) {
          float v = fmaxf(acc[mt][nt][e] + bv, 0.f);
          int row = mt * 32 + (e & 3) + 8 * (e >> 2) + 4 * hi;
          *(f16*)(myc + row * 128 + (cb ^ ((row & 7) << 4))) = (f16)v;
        }
    }
  }
  __syncthreads();   // B5: h2 ready

  // ---------------- head GEMM: waves 0..3, wave w -> rows 16w..16w+15 ----
  if (w < 4) {
    const int base_m = (m == 0) ? 0 : (m == 1) ? 1 : (m == 2) ? 7 : 11;
    const int cnt_m  = (m == 0) ? 1 : (m == 1) ? 6 : (m == 2) ? 4 : 12;
    const bool ovalid = l15 < cnt_m;
    const f16* w3row = w3f16 + (size_t)(base_m + (ovalid ? l15 : 0)) * DH;
    floatx4 acc3 = {0.f, 0.f, 0.f, 0.f};
#pragma unroll 2
    for (int q = 0; q < 16; ++q) {
      half8 ah = aread16(q, w);
      half8 wv = ovalid ? *(const half8*)(w3row + q * 32 + lg * 8) : hz;
      acc3 = __builtin_amdgcn_mfma_f32_16x16x32_f16(ah, wv, acc3, 0, 0, 0);
    }
    if (ovalid) {
      const float bo = b3g[base_m + l15];
#pragma unroll
      for (int j = 0; j < 4; ++j) {
        const int row = r0 + w * 16 + 4 * lg + j;
        const float v = acc3[j] + bo;
        if (m == 0)      { if (l15 == 0) dout[row] = v; }
        else if (m == 1) { dout[KROWS + row * 18 + (l15 < 3 ? l15 : l15 + 6)] = v; }
        else if (m == 2) { pred2d[row * 4 + l15] = v; }
        else             { dout[KROWS + row * 18 + (l15 < 6 ? l15 + 3 : l15 + 6)] = v; }
      }
    }
  }
}

// ---------------------------------------------------------------------------
// Loss math helpers (scalar fp32, matches jnp reference)
// ---------------------------------------------------------------------------
__device__ __forceinline__ void safe_norm3(float x, float y, float z, float* o) {
  float n = sqrtf(x * x + y * y + z * z);
  if (n > 1e-6f) { o[0] = x / n; o[1] = y / n; o[2] = z / n; }
  else           { o[0] = 1.f;   o[1] = 0.f;   o[2] = 0.f; }
}

__device__ __forceinline__ void rot6d(const float* x, float* R) {
  float a1[3]; safe_norm3(x[0], x[1], x[2], a1);
  float d = a1[0] * x[3] + a1[1] * x[4] + a1[2] * x[5];
  float b2[3]; safe_norm3(x[3] - d * a1[0], x[4] - d * a1[1], x[5] - d * a1[2], b2);
  float a3[3];
  safe_norm3(a1[1] * b2[2] - a1[2] * b2[1],
             a1[2] * b2[0] - a1[0] * b2[2],
             a1[0] * b2[1] - a1[1] * b2[0], a3);
  float bb[3];
  safe_norm3(a3[1] * a1[2] - a3[2] * a1[1],
             a3[2] * a1[0] - a3[0] * a1[2],
             a3[0] * a1[1] - a3[1] * a1[0], bb);
  R[0] = a1[0]; R[1] = a1[1]; R[2] = a1[2];
  R[3] = bb[0]; R[4] = bb[1]; R[5] = bb[2];
  R[6] = a3[0]; R[7] = a3[1]; R[8] = a3[2];
}

__device__ __forceinline__ float geo_angle(const float* P, const float* G) {
  float M[9];
#pragma unroll
  for (int i = 0; i < 3; ++i)
#pragma unroll
    for (int l = 0; l < 3; ++l)
      M[i * 3 + l] = G[0 + i] * P[0 + l] + G[3 + i] * P[3 + l] + G[6 + i] * P[6 + l];
  float tr = M[0] + M[4] + M[8];
  float c = fminf(fmaxf((tr - 1.f) * 0.5f, -1.f + 1e-6f), 1.f - 1e-6f);
  float v0 = M[7] - M[5], v1 = M[2] - M[6], v2 = M[3] - M[1];
  float s = 0.5f * sqrtf(v0 * v0 + v1 * v1 + v2 * v2) + 1e-8f;
  return atan2f(s, c);
}

// accumulators: 0 t_num 1 t_den 2 tv_sum 3..6 n3T d3T n3F d3F
//               7..10 n2T d2T n2F d2F  11..14 nqT dqT nqF dqF  15 rot_num 16 rot_den
__global__ __launch_bounds__(256) void loss_partial(
    const float* __restrict__ gt, const float* __restrict__ dout,
    const float* __restrict__ pred2d, float* __restrict__ partials)
{
  const int r = blockIdx.x * 256 + threadIdx.x;
  const float* g  = gt + (size_t)r * 23;
  const float* pk = dout + KROWS + (size_t)r * 18;
  float a[17];

  const float pt = dout[r];
  const float tg = g[0];
  const float tv = (tg != -1000.f) ? 1.f : 0.f;
  const float dt = fabsf(pt - tg);
  a[0] = ((dt < 3.f) ? (0.5f * dt * dt / 3.f) : (dt - 1.5f)) * tv;
  a[1] = tv;
  a[2] = tv;
  const float wt = expf(-0.5f * (dt / 3.f) * (dt / 3.f)) * tv;

  float n3T = 0.f, d3T = 0.f, n3F = 0.f, d3F = 0.f;
#pragma unroll
  for (int j = 0; j < 6; ++j) {
    const float p = pk[j < 3 ? j : j + 6];
    const float q = g[1 + j];
    const float val = (q != -1000.f) ? 1.f : 0.f;
    const float d = fabsf(p - q);
    const float l = (d < 0.07f) ? (0.5f * d * d / 0.07f) : (d - 0.035f);
    n3T += l * val * wt; d3T += val * wt; n3F += l * val; d3F += val;
  }
  a[3] = n3T; a[4] = d3T; a[5] = n3F; a[6] = d3F;

  float n2T = 0.f, d2T = 0.f, n2F = 0.f, d2F = 0.f;
#pragma unroll
  for (int j = 0; j < 4; ++j) {
    const float p = pred2d[(size_t)r * 4 + j];
    const float q = g[7 + j];
    const float val = (q != -1000.f) ? 1.f : 0.f;
    const float d = fabsf(p / 1408.f - q / 1408.f);
    const float l = (d < 0.02f) ? (0.5f * d * d / 0.02f) : (d - 0.01f);
    n2T += l * val * wt; d2T += val * wt; n2F += l * val; d2F += val;
  }
  a[7] = n2T; a[8] = d2T; a[9] = n2F; a[10] = d2F;

  float qp[12];
#pragma unroll
  for (int j = 0; j < 12; ++j) qp[j] = pk[j < 6 ? j + 3 : j + 6];
  float nqT = 0.f, dqT = 0.f, nqF = 0.f, dqF = 0.f;
#pragma unroll
  for (int j = 0; j < 12; ++j) {
    const float q = g[11 + j];
    const float val = (q != -1000.f) ? 1.f : 0.f;
    const float d = fabsf(qp[j] - q);
    const float l = (d < 0.2f) ? (0.5f * d * d / 0.2f) : (d - 0.1f);
    nqT += l * val * wt; dqT += val * wt; nqF += l * val; dqF += val;
  }
  a[11] = nqT; a[12] = dqT; a[13] = nqF; a[14] = dqF;

  bool Lv = true, Rv = true;
#pragma unroll
  for (int j = 0; j < 6; ++j) {
    if (g[11 + j] == -1000.f) Lv = false;
    if (g[17 + j] == -1000.f) Rv = false;
  }
  const float safe6[6] = {1.f, 0.f, 0.f, 0.f, 1.f, 0.f};
  float Lt[6], Rt[6];
#pragma unroll
  for (int j = 0; j < 6; ++j) {
    Lt[j] = Lv ? g[11 + j] : safe6[j];
    Rt[j] = Rv ? g[17 + j] : safe6[j];
  }
  float Rp[9], Rg[9];
  rot6d(qp, Rp);     rot6d(Lt, Rg);
  const float angL = geo_angle(Rp, Rg);
  rot6d(qp + 6, Rp); rot6d(Rt, Rg);
  const float angR = geo_angle(Rp, Rg);
  a[15] = (Lv ? angL : 0.f) + (Rv ? angR : 0.f);
  a[16] = (Lv ? 1.f : 0.f) + (Rv ? 1.f : 0.f);

#pragma unroll
  for (int i = 0; i < 17; ++i) {
    float v = a[i];
#pragma unroll
    for (int off = 32; off > 0; off >>= 1) v += __shfl_down(v, off, 64);
    a[i] = v;
  }
  __shared__ float red[4][17];
  if ((threadIdx.x & 63) == 0) {
    const int wv = threadIdx.x >> 6;
#pragma unroll
    for (int i = 0; i < 17; ++i) red[wv][i] = a[i];
  }
  __syncthreads();
  if (threadIdx.x < 17)
    partials[blockIdx.x * 20 + threadIdx.x] =
        red[0][threadIdx.x] + red[1][threadIdx.x] + red[2][threadIdx.x] + red[3][threadIdx.x];
}

__global__ void loss_final(const float* __restrict__ partials, float* __restrict__ dout)
{
  __shared__ float s[17];
  const int i = threadIdx.x;
  if (i < 17) {
    float v = 0.f;
    for (int b = 0; b < 256; ++b) v += partials[b * 20 + i];
    s[i] = v;
  }
  __syncthreads();
  if (i == 0) {
    const bool flag = s[2] > 0.f;
    const float time_loss = s[0] / fmaxf(s[1], 1.f);
    const float l3 = flag ? s[3] / fmaxf(s[4], 1.f) : s[5] / fmaxf(s[6], 1.f);
    const float l2 = flag ? s[7] / fmaxf(s[8], 1.f) : s[9] / fmaxf(s[10], 1.f);
    const float lq = flag ? s[11] / fmaxf(s[12], 1.f) : s[13] / fmaxf(s[14], 1.f);
    const float rot = 0.15f * (s[15] / fmaxf(s[16], 1e-8f));
    dout[19 * KROWS] = time_loss + 2.f * l3 + 0.5f * l2 + 0.5f * lq + rot;
  }
}

// ---------------------------------------------------------------------------
extern "C" void kernel_launch(void* const* d_in, const int* in_sizes, int n_in,
                              void* d_out, int out_size, void* d_ws, size_t ws_size,
                              hipStream_t stream) {
  (void)in_sizes; (void)n_in; (void)out_size; (void)ws_size;
  const float* hidden = (const float*)d_in[0];
  const float* gt     = (const float*)d_in[1];
  const float* w1     = (const float*)d_in[2];
  const float* b1     = (const float*)d_in[3];
  const float* w2     = (const float*)d_in[4];
  const float* b2     = (const float*)d_in[5];
  const float* w3     = (const float*)d_in[6];
  const float* b3     = (const float*)d_in[7];
  float* dout = (float*)d_out;

  unsigned char* ws = (unsigned char*)d_ws;
  f16*   wf16     = (f16*)(ws + WS_WF16);
  f16*   w3f16    = (f16*)(ws + WS_W3F16);
  float* pred2d   = (float*)(ws + WS_PRED2D);
  float* partials = (float*)(ws + WS_PART);

  convert_weights<<<1070, 256, 0, stream>>>(w1, w2, w3, wf16, w3f16);
  fused_kernel<<<4096, 512, 0, stream>>>(hidden, wf16, w3f16, b1, b2, b3, dout, pred2d);
  loss_partial<<<256, 256, 0, stream>>>(gt, dout, pred2d, partials);
  loss_final<<<1, 64, 0, stream>>>(partials, dout);
}